// Round 1
// 89.224 us; speedup vs baseline: 1.0631x; 1.0631x over previous
//
#include <hip/hip_runtime.h>
#include <math.h>

#define N_ROWS 2048
#define D_DIM 512
#define P_DIM 10

__device__ inline float wave_reduce_f(float v) {
#pragma unroll
  for (int off = 32; off > 0; off >>= 1) v += __shfl_down(v, off, 64);
  return v;
}

__device__ inline double wave_reduce_d(double v) {
#pragma unroll
  for (int off = 32; off > 0; off >>= 1) v += __shfl_down(v, off, 64);
  return v;
}

// K1: wave-per-row. Computes post_cm[p][row] = z[row,:]@proj[:,p] and
// prior_cm[p][row] = (gmm_noise[row,:]/max(||row||,eps))@proj[:,p].
// proj staged transposed in LDS as [p][k] so lane-stride-1 LDS reads are
// conflict-free (2 lanes/bank = free on gfx950).
__global__ __launch_bounds__(256) void rc_proj_kernel(
    const float* __restrict__ z, const float* __restrict__ g,
    const float* __restrict__ proj, float* __restrict__ post_cm,
    float* __restrict__ prior_cm) {
  __shared__ float pl[P_DIM * D_DIM];  // [p][k], 20 KiB
  for (int i = threadIdx.x; i < P_DIM * D_DIM; i += 256) {
    int k = i / P_DIM, p = i - k * P_DIM;
    pl[p * D_DIM + k] = proj[i];
  }
  __syncthreads();
  const int wave = threadIdx.x >> 6, lane = threadIdx.x & 63;
  const int row = blockIdx.x * 4 + wave;
  const float* zr = z + (size_t)row * D_DIM;
  const float* gr = g + (size_t)row * D_DIM;
  float zv[8], gv[8];
#pragma unroll
  for (int m = 0; m < 8; ++m) {  // coalesced: lane-stride-1, 4B/lane
    zv[m] = zr[m * 64 + lane];
    gv[m] = gr[m * 64 + lane];
  }
  float n2 = 0.f;
#pragma unroll
  for (int m = 0; m < 8; ++m) n2 += gv[m] * gv[m];
  float az[P_DIM], ag[P_DIM];
#pragma unroll
  for (int p = 0; p < P_DIM; ++p) { az[p] = 0.f; ag[p] = 0.f; }
#pragma unroll
  for (int m = 0; m < 8; ++m) {
#pragma unroll
    for (int p = 0; p < P_DIM; ++p) {
      float w = pl[p * D_DIM + m * 64 + lane];
      az[p] += zv[m] * w;
      ag[p] += gv[m] * w;
    }
  }
#pragma unroll
  for (int p = 0; p < P_DIM; ++p) {
    az[p] = wave_reduce_f(az[p]);
    ag[p] = wave_reduce_f(ag[p]);
  }
  n2 = wave_reduce_f(n2);
  if (lane == 0) {
    float inv = 1.f / fmaxf(sqrtf(n2), 1e-12f);
    for (int p = 0; p < P_DIM; ++p) {
      post_cm[p * N_ROWS + row] = az[p];
      prior_cm[p * N_ROWS + row] = ag[p] * inv;
    }
  }
}

// K2: fused sort+stats. One block per projection p. Sorts BOTH post column p
// and prior column p with a register/shuffle bitonic network:
//   - j < 64   : within-wave via __shfl_xor (51 of 66 phases, no barrier)
//   - j = 1024 : pairs (tid, tid+1024) live in the same thread (in-register)
//   - j = 64..512 : cross-wave via ping-pong LDS (14 phases, 1 barrier each)
// Then computes both fgw variants' statistics (f64) directly from registers;
// the reversed pairing of variant 2 is one LDS bounce. Writes min(fgw1,fgw2).
__global__ __launch_bounds__(1024) void rc_sortstats_kernel(
    const float* __restrict__ post_cm, const float* __restrict__ prior_cm,
    float* __restrict__ fgw) {
  const int p = blockIdx.x;
  const int tid = threadIdx.x;
  const int lane = tid & 63;
  __shared__ float sA[2][N_ROWS];  // ping-pong, post
  __shared__ float sB[2][N_ROWS];  // ping-pong, prior
  __shared__ double smd[16][14];

  float a0 = post_cm[p * N_ROWS + tid];
  float a1 = post_cm[p * N_ROWS + tid + 1024];
  float b0 = prior_cm[p * N_ROWS + tid];
  float b1 = prior_cm[p * N_ROWS + tid + 1024];
  int cb = 0;

  auto shfl_phase = [&](unsigned j, unsigned k) {
    // j < 64: partner is lane^j within the same wave, same register slot.
    bool lo = ((lane & (int)j) == 0);          // (idx & j) for both regs
    bool up0 = ((tid & (int)k) == 0);
    bool up1 = (((tid + 1024) & (int)k) == 0);
    float t;
    t = __shfl_xor(a0, (int)j, 64);
    a0 = (lo == up0) ? fminf(a0, t) : fmaxf(a0, t);
    t = __shfl_xor(a1, (int)j, 64);
    a1 = (lo == up1) ? fminf(a1, t) : fmaxf(a1, t);
    t = __shfl_xor(b0, (int)j, 64);
    b0 = (lo == up0) ? fminf(b0, t) : fmaxf(b0, t);
    t = __shfl_xor(b1, (int)j, 64);
    b1 = (lo == up1) ? fminf(b1, t) : fmaxf(b1, t);
  };

  auto lds_phase = [&](unsigned j, unsigned k) {
    // 64 <= j <= 512: cross-wave. Write regs, barrier, read partner.
    // Ping-pong buffer => exactly one barrier per phase (next phase writes
    // the other buffer, so laggard readers of this buffer are safe).
    float* A = sA[cb];
    float* B = sB[cb];
    A[tid] = a0;
    A[tid + 1024] = a1;
    B[tid] = b0;
    B[tid + 1024] = b1;
    __syncthreads();
    unsigned i0 = (unsigned)tid, i1 = (unsigned)tid + 1024u;
    float qa0 = A[i0 ^ j], qa1 = A[i1 ^ j];
    float qb0 = B[i0 ^ j], qb1 = B[i1 ^ j];
    bool lo0 = ((i0 & j) == 0), lo1 = ((i1 & j) == 0);
    bool up0 = ((i0 & k) == 0), up1 = ((i1 & k) == 0);
    a0 = (lo0 == up0) ? fminf(a0, qa0) : fmaxf(a0, qa0);
    a1 = (lo1 == up1) ? fminf(a1, qa1) : fmaxf(a1, qa1);
    b0 = (lo0 == up0) ? fminf(b0, qb0) : fmaxf(b0, qb0);
    b1 = (lo1 == up1) ? fminf(b1, qb1) : fmaxf(b1, qb1);
    cb ^= 1;
  };

  // Stages k = 2..64: entirely within-wave (21 phases, zero barriers).
#pragma unroll
  for (unsigned k = 2; k <= 64; k <<= 1)
#pragma unroll
    for (unsigned j = k >> 1; j >= 1; j >>= 1) shfl_phase(j, k);
  // Stages k = 128..2048.
#pragma unroll
  for (unsigned k = 128; k <= 2048; k <<= 1) {
#pragma unroll
    for (unsigned j = k >> 1; j >= 64; j >>= 1) {
      if (j == 1024) {
        // pairs (tid, tid+1024): both in this thread; k=2048 => ascending
        float na = fminf(a0, a1);
        a1 = fmaxf(a0, a1);
        a0 = na;
        float nb = fminf(b0, b1);
        b1 = fmaxf(b0, b1);
        b0 = nb;
      } else {
        lds_phase(j, k);
      }
    }
#pragma unroll
    for (unsigned j = 32; j >= 1; j >>= 1) shfl_phase(j, k);
  }

  // ---- fused stats ----
  __syncthreads();  // drain last lds_phase readers before reusing sB[0]
  float* Bs = sB[0];
  Bs[tid] = b0;
  Bs[tid + 1024] = b1;
  __syncthreads();
  float br0 = Bs[2047 - tid];  // pairs with a0 (idx = tid)
  float br1 = Bs[1023 - tid];  // pairs with a1 (idx = tid+1024)

  // Shared sums: S0=Σa S1=Σb S2=Σa² S3=Σb² (pairing-invariant; Σs = S2-S3,
  // Σbr = Σb, Σbr² = Σb²). Variant sums: Σs², Σs·a, Σs·b, Σab, Σ(a-b)².
  double S[14];
  {
    double av0 = a0, av1 = a1, bv0 = b0, bv1 = b1, bw0 = br0, bw1 = br1;
    double a20 = av0 * av0, a21 = av1 * av1;
    double b20 = bv0 * bv0, b21 = bv1 * bv1;
    double c20 = bw0 * bw0, c21 = bw1 * bw1;
    double s10 = a20 - b20, s11 = a21 - b21;
    double s20 = a20 - c20, s21 = a21 - c21;
    S[0] = av0 + av1;
    S[1] = bv0 + bv1;
    S[2] = a20 + a21;
    S[3] = b20 + b21;
    S[4] = s10 * s10 + s11 * s11;
    S[5] = s10 * av0 + s11 * av1;
    S[6] = s10 * bv0 + s11 * bv1;
    S[7] = av0 * bv0 + av1 * bv1;
    double d10 = av0 - bv0, d11 = av1 - bv1;
    S[8] = d10 * d10 + d11 * d11;
    S[9] = s20 * s20 + s21 * s21;
    S[10] = s20 * av0 + s21 * av1;
    S[11] = s20 * bw0 + s21 * bw1;
    S[12] = av0 * bw0 + av1 * bw1;
    double d20 = av0 - bw0, d21 = av1 - bw1;
    S[13] = d20 * d20 + d21 * d21;
  }
#pragma unroll
  for (int t = 0; t < 14; ++t) S[t] = wave_reduce_d(S[t]);
  const int wv = tid >> 6;
  if (lane == 0) {
#pragma unroll
    for (int t = 0; t < 14; ++t) smd[wv][t] = S[t];
  }
  __syncthreads();
  if (tid == 0) {
    double T[14];
#pragma unroll
    for (int t = 0; t < 14; ++t) {
      double acc = 0.0;
      for (int w = 0; w < 16; ++w) acc += smd[w][t];
      T[t] = acc;
    }
    const double nn = (double)N_ROWS;
    double Ss = T[2] - T[3];  // Σ(a²-b²), same for both variants
    double gw1 = (2.0 * nn * T[4] + 2.0 * Ss * Ss -
                  8.0 * (T[5] * T[0] - T[6] * T[1]) +
                  4.0 * (T[2] * T[2] - 2.0 * T[7] * T[7] + T[3] * T[3])) /
                 (nn * nn);
    double gw2 = (2.0 * nn * T[9] + 2.0 * Ss * Ss -
                  8.0 * (T[10] * T[0] - T[11] * T[1]) +
                  4.0 * (T[2] * T[2] - 2.0 * T[12] * T[12] + T[3] * T[3])) /
                 (nn * nn);
    double f1 = 0.9 * T[8] + 0.1 * gw1;
    double f2 = 0.9 * T[13] + 0.1 * gw2;
    fgw[p] = (float)fmin(f1, f2);
  }
}

// K3: out = mean_p fgw[p]
__global__ void rc_final_kernel(const float* __restrict__ fgw,
                                float* __restrict__ out) {
  if (threadIdx.x == 0 && blockIdx.x == 0) {
    float s = 0.f;
    for (int p = 0; p < P_DIM; ++p) s += fgw[p];
    out[0] = s * (1.f / P_DIM);
  }
}

extern "C" void kernel_launch(void* const* d_in, const int* in_sizes, int n_in,
                              void* d_out, int out_size, void* d_ws,
                              size_t ws_size, hipStream_t stream) {
  const float* z = (const float*)d_in[0];
  const float* g = (const float*)d_in[1];
  const float* proj = (const float*)d_in[2];
  float* out = (float*)d_out;
  float* post_cm = (float*)d_ws;               // 2048*10 f32
  float* prior_cm = post_cm + N_ROWS * P_DIM;  // 2048*10 f32
  float* fgw = prior_cm + N_ROWS * P_DIM;      // 10 f32

  rc_proj_kernel<<<N_ROWS / 4, 256, 0, stream>>>(z, g, proj, post_cm,
                                                 prior_cm);
  rc_sortstats_kernel<<<P_DIM, 1024, 0, stream>>>(post_cm, prior_cm, fgw);
  rc_final_kernel<<<1, 64, 0, stream>>>(fgw, out);
}